// Round 2
// baseline (100.627 us; speedup 1.0000x reference)
//
#include <hip/hip_runtime.h>

#define HH 512
#define WW 512
#define NB 16
#define RPB 8
#define NCHUNK (HH / RPB)      // 64 row-chunks per batch item
#define NBLOCKS (NB * NCHUNK)  // 1024 partials

// One block per (batch, 8-row chunk). Uniform branch per block (dx per-batch).
// Each thread: 4 consecutive pixels in one row; 256 threads cover 2 rows/iter.
__global__ __launch_bounds__(256) void mbfs_main(
    const float* __restrict__ grid,
    const float* __restrict__ gt,
    const float* __restrict__ gd,
    const float* __restrict__ mask,
    float* __restrict__ partials)
{
    const int b     = blockIdx.y;
    const int chunk = blockIdx.x;
    const int row0  = chunk * RPB;

    const float dx   = -8.0f * gt[2 * b + 0];
    const float dy   =  8.0f * gt[2 * b + 1];
    const float symx = gd[2 * b + 0];
    const float symy = gd[2 * b + 1];

    const float dy1f = floorf(dy);
    const float dx1f = floorf(dx);
    const int dy1 = (int)dy1f;
    const int dx1 = (int)dx1f;
    const int dy2 = dy1 + 1;
    const int dx2 = dx1 + 1;
    const float wc1 = (dx1f + 1.0f) - dx;
    const float wc2 = dx - dx1f;
    const float wr1 = (dy1f + 1.0f) - dy;
    const float wr2 = dy - dy1f;

    const float* g0 = grid + (size_t)b * 2 * HH * WW;
    const float* g1 = g0 + HH * WW;
    const float* mk = mask + (size_t)b * HH * WW;

    const int imax = HH - dy2;
    const int rsub = threadIdx.x >> 7;        // 0..1 : which of 2 rows
    const int j0   = (threadIdx.x & 127) << 2; // 0..508, 16B aligned
    const int rend = min(row0 + RPB, imax);

    float acc = 0.0f;
    float cnt;

    if (dx > 0.0f) {
        // delta_p = g[i][j] - (wc1*z[j+dx1] + wc2*z[j+dx1+1]),
        // z[c] = wr1*g[i+dy1][c] + wr2*g[i+dy2][c]. All valid-region indices
        // in range; clamp only covers masked-out tail pixels.
        const int jmax = WW - dx2;
        cnt = (float)imax * (float)jmax;
        for (int i = row0 + rsub; i < rend; i += 2) {
            const float* gc0 = g0 + i * WW;
            const float* gc1 = g1 + i * WW;
            const float* ga0 = g0 + (i + dy1) * WW;
            const float* gb0 = g0 + (i + dy2) * WW;
            const float* ga1 = g1 + (i + dy1) * WW;
            const float* gb1 = g1 + (i + dy2) * WW;
            const float* mr  = mk + i * WW;

            const float4 c0 = *(const float4*)(gc0 + j0);
            const float4 c1 = *(const float4*)(gc1 + j0);
            const float4 mv = *(const float4*)(mr + j0);

            float z0[5], z1[5];
            #pragma unroll
            for (int k = 0; k < 5; ++k) {
                int col = j0 + dx1 + k;
                col = min(col, WW - 1);
                z0[k] = wr1 * ga0[col] + wr2 * gb0[col];
                z1[k] = wr1 * ga1[col] + wr2 * gb1[col];
            }
            const float cc0[4] = {c0.x, c0.y, c0.z, c0.w};
            const float cc1[4] = {c1.x, c1.y, c1.z, c1.w};
            const float mm[4]  = {mv.x, mv.y, mv.z, mv.w};
            #pragma unroll
            for (int k = 0; k < 4; ++k) {
                float s0 = wc1 * z0[k] + wc2 * z0[k + 1];
                float s1 = wc1 * z1[k] + wc2 * z1[k + 1];
                float d0 = cc0[k] - s0;
                float d1 = cc1[k] - s1;
                float e  = d0 * symy + d1 * symx;
                float w  = (j0 + k < jmax) ? mm[k] : 0.0f;
                acc += w * e * e;
            }
        }
    } else {
        // delta_n = wc1*g[i+dy2][j] + wc2*g[i+dy2][clip(j+1)]
        //         - (wr1*g[i+1][jm] + wr2*g[i][jm]),  jm = j - dx1 (dx1<=0)
        // mask sampled at [i+dy2][jm].
        const int a    = -dx1;               // 0..8
        const int jmax = WW + dx1;
        cnt = (float)imax * (float)jmax;
        for (int i = row0 + rsub; i < rend; i += 2) {
            const float* r20  = g0 + (i + dy2) * WW;
            const float* r21  = g1 + (i + dy2) * WW;
            const float* ri0  = g0 + i * WW;
            const float* ri10 = g0 + (i + 1) * WW;
            const float* ri1  = g1 + i * WW;
            const float* ri11 = g1 + (i + 1) * WW;
            const float* mr   = mk + (i + dy2) * WW;

            const float4 h0 = *(const float4*)(r20 + j0);
            const float4 h1 = *(const float4*)(r21 + j0);
            const int je = min(j0 + 4, WW - 1);
            const float h0e = r20[je];
            const float h1e = r21[je];

            float zn0[4], zn1[4], mm[4];
            #pragma unroll
            for (int k = 0; k < 4; ++k) {
                int jm = min(j0 + k + a, WW - 1);
                zn0[k] = wr1 * ri10[jm] + wr2 * ri0[jm];
                zn1[k] = wr1 * ri11[jm] + wr2 * ri1[jm];
                mm[k]  = mr[jm];
            }
            const float hh0[5] = {h0.x, h0.y, h0.z, h0.w, h0e};
            const float hh1[5] = {h1.x, h1.y, h1.z, h1.w, h1e};
            #pragma unroll
            for (int k = 0; k < 4; ++k) {
                float d0 = wc1 * hh0[k] + wc2 * hh0[k + 1] - zn0[k];
                float d1 = wc1 * hh1[k] + wc2 * hh1[k + 1] - zn1[k];
                float e  = d0 * symy + d1 * symx;
                float w  = (j0 + k < jmax) ? mm[k] : 0.0f;
                acc += w * e * e;
            }
        }
    }

    // Block reduction: wave64 shuffle, then LDS across the 4 waves.
    #pragma unroll
    for (int off = 32; off > 0; off >>= 1)
        acc += __shfl_down(acc, off, 64);
    __shared__ float part[4];
    const int lane = threadIdx.x & 63;
    const int wv   = threadIdx.x >> 6;
    if (lane == 0) part[wv] = acc;
    __syncthreads();
    if (threadIdx.x == 0) {
        float s = part[0] + part[1] + part[2] + part[3];
        partials[b * NCHUNK + chunk] = s / (cnt * (float)NB);
    }
}

__global__ __launch_bounds__(256) void mbfs_reduce(
    const float* __restrict__ partials, float* __restrict__ out)
{
    float v = 0.0f;
    for (int idx = threadIdx.x; idx < NBLOCKS; idx += 256) v += partials[idx];
    #pragma unroll
    for (int off = 32; off > 0; off >>= 1)
        v += __shfl_down(v, off, 64);
    __shared__ float part[4];
    const int lane = threadIdx.x & 63;
    const int wv   = threadIdx.x >> 6;
    if (lane == 0) part[wv] = v;
    __syncthreads();
    if (threadIdx.x == 0) out[0] = part[0] + part[1] + part[2] + part[3];
}

extern "C" void kernel_launch(void* const* d_in, const int* in_sizes, int n_in,
                              void* d_out, int out_size, void* d_ws, size_t ws_size,
                              hipStream_t stream) {
    const float* grid_p = (const float*)d_in[0];  // (16, 2, 512, 512)
    const float* gt_p   = (const float*)d_in[1];  // (16, 2)
    const float* gd_p   = (const float*)d_in[2];  // (16, 2)
    const float* mask_p = (const float*)d_in[3];  // (16, 512, 512)
    float* out_p = (float*)d_out;
    float* ws_p  = (float*)d_ws;                  // NBLOCKS floats of partials

    dim3 g(NCHUNK, NB);
    mbfs_main<<<g, 256, 0, stream>>>(grid_p, gt_p, gd_p, mask_p, ws_p);
    mbfs_reduce<<<1, 256, 0, stream>>>(ws_p, out_p);
}

// Round 3
// 97.611 us; speedup vs baseline: 1.0309x; 1.0309x over previous
//
#include <hip/hip_runtime.h>

#define HH 512
#define WW 512
#define NB 16
#define NRB 2                      // output rows per block
#define NCHUNK (HH / NRB)          // 256 blocks per batch item
#define NBLOCKS (NB * NCHUNK)      // 4096 partials

// Swizzled LDS layout within a 512-float row: col c -> (c&3)*128 + c/4.
// Staging writes (thread f handles cols 4f..4f+3) land at lane-stride-1;
// compute reads (lane jt reads col 4*jt + shift + k, shift wave-uniform)
// also land at lane-stride-1 -> conflict-free both ways.
__device__ __forceinline__ int swz(int c) { return ((c & 3) << 7) | (c >> 2); }

// One block = (batch b, 2 output rows). Branch on dx is uniform per block.
// Each thread: exactly one group of 4 consecutive pixels in one row.
__global__ __launch_bounds__(256) void mbfs_main(
    const float* __restrict__ grid,
    const float* __restrict__ gt,
    const float* __restrict__ gd,
    const float* __restrict__ mask,
    float* __restrict__ partials)
{
    __shared__ float lds[6 * 512];   // 12 KiB (positive branch uses 6 rows, negative 4)

    const int b    = blockIdx.y;
    const int i0   = blockIdx.x * NRB;
    const int tid  = threadIdx.x;
    const int rsub = tid >> 7;        // which of the 2 rows
    const int jt   = tid & 127;
    const int j0   = jt << 2;         // 0..508, 16B aligned

    const float dx   = -8.0f * gt[2 * b + 0];
    const float dy   =  8.0f * gt[2 * b + 1];
    const float symx = gd[2 * b + 0];
    const float symy = gd[2 * b + 1];

    const float dy1f = floorf(dy);
    const float dx1f = floorf(dx);
    const int dy1 = (int)dy1f;
    const int dx1 = (int)dx1f;
    const int dy2 = dy1 + 1;
    const int dx2 = dx1 + 1;
    const float wc1 = (dx1f + 1.0f) - dx;
    const float wc2 = dx - dx1f;
    const float wr1 = (dy1f + 1.0f) - dy;
    const float wr2 = dy - dy1f;

    const float* g0 = grid + (size_t)b * 2 * HH * WW;
    const float* g1 = g0 + HH * WW;
    const float* mk = mask + (size_t)b * HH * WW;

    const int imax = HH - dy2;        // rows valid for i < imax (both branches)
    float acc = 0.0f;
    float cnt;

    if (dx > 0.0f) {
        // delta_p = g[i][j] - (wc1*z[j+dx1] + wc2*z[j+dx1+1]),
        // z[c] = wr1*g[i+dy1][c] + wr2*g[i+dy2][c].
        const int jmax = WW - dx2;
        cnt = (float)imax * (float)jmax;

        // Stage 6 shifted rows: s=0..2 -> ch0 rows i0+dy1+s ; s=3..5 -> ch1.
        for (int t = tid; t < 6 * 128; t += 256) {
            const int s  = t >> 7;
            const int f  = t & 127;
            const int c  = f << 2;
            const int rr = (s < 3) ? s : s - 3;
            const float* gp = (s < 3) ? g0 : g1;
            int ir = min(i0 + dy1 + rr, HH - 1);
            const float4 v = *(const float4*)(gp + ir * WW + c);
            float* L = lds + s * 512;
            L[swz(c)]     = v.x;
            L[swz(c + 1)] = v.y;
            L[swz(c + 2)] = v.z;
            L[swz(c + 3)] = v.w;
        }
        __syncthreads();

        const int i = i0 + rsub;
        if (i < imax) {
            const float4 c0 = *(const float4*)(g0 + i * WW + j0);
            const float4 c1 = *(const float4*)(g1 + i * WW + j0);
            const float4 mv = *(const float4*)(mk + i * WW + j0);
            const float* A0 = lds + rsub * 512;
            const float* B0 = lds + (rsub + 1) * 512;
            const float* A1 = lds + (3 + rsub) * 512;
            const float* B1 = lds + (4 + rsub) * 512;

            float z0[5], z1[5];
            #pragma unroll
            for (int k = 0; k < 5; ++k) {
                const int c  = min(j0 + dx1 + k, WW - 1);
                const int sc = swz(c);
                z0[k] = wr1 * A0[sc] + wr2 * B0[sc];
                z1[k] = wr1 * A1[sc] + wr2 * B1[sc];
            }
            const float cc0[4] = {c0.x, c0.y, c0.z, c0.w};
            const float cc1[4] = {c1.x, c1.y, c1.z, c1.w};
            const float mm[4]  = {mv.x, mv.y, mv.z, mv.w};
            #pragma unroll
            for (int k = 0; k < 4; ++k) {
                const float s0 = wc1 * z0[k] + wc2 * z0[k + 1];
                const float s1 = wc1 * z1[k] + wc2 * z1[k + 1];
                const float d0 = cc0[k] - s0;
                const float d1 = cc1[k] - s1;
                const float e  = d0 * symy + d1 * symx;
                const float w  = (j0 + k < jmax) ? mm[k] : 0.0f;
                acc += w * e * e;
            }
        }
    } else {
        // Negative branch, iterated on j' = j - dx1 (aligned):
        // delta_n = wc1*h[j'-a] + wc2*h[j'-a+1] - (wr1*g[i+1][j'] + wr2*g[i][j'])
        // with h = g[i+dy2][.], a = -dx1 >= 0; mask at [i+dy2][j']; valid j' >= a.
        const int a    = -dx1;
        const int jmax = WW + dx1;
        cnt = (float)imax * (float)jmax;

        // Stage 4 h-rows: s=0..1 -> ch0 rows i0+dy2+s ; s=2..3 -> ch1.
        for (int t = tid; t < 4 * 128; t += 256) {
            const int s  = t >> 7;
            const int f  = t & 127;
            const int c  = f << 2;
            const int rr = s & 1;
            const float* gp = (s < 2) ? g0 : g1;
            int ir = min(i0 + dy2 + rr, HH - 1);
            const float4 v = *(const float4*)(gp + ir * WW + c);
            float* L = lds + s * 512;
            L[swz(c)]     = v.x;
            L[swz(c + 1)] = v.y;
            L[swz(c + 2)] = v.z;
            L[swz(c + 3)] = v.w;
        }
        __syncthreads();

        const int i = i0 + rsub;
        if (i < imax) {
            const float4 p00 = *(const float4*)(g0 + i * WW + j0);        // g0(i, j')
            const float4 p01 = *(const float4*)(g0 + (i + 1) * WW + j0);  // g0(i+1, j')
            const float4 p10 = *(const float4*)(g1 + i * WW + j0);
            const float4 p11 = *(const float4*)(g1 + (i + 1) * WW + j0);
            const float4 mv  = *(const float4*)(mk + (i + dy2) * WW + j0);
            const float* H0 = lds + rsub * 512;
            const float* H1 = lds + (2 + rsub) * 512;

            float hh0[5], hh1[5];
            #pragma unroll
            for (int k = 0; k < 5; ++k) {
                int c = j0 - a + k;
                c = max(0, min(c, WW - 1));
                const int sc = swz(c);
                hh0[k] = H0[sc];
                hh1[k] = H1[sc];
            }
            const float q00[4] = {p00.x, p00.y, p00.z, p00.w};
            const float q01[4] = {p01.x, p01.y, p01.z, p01.w};
            const float q10[4] = {p10.x, p10.y, p10.z, p10.w};
            const float q11[4] = {p11.x, p11.y, p11.z, p11.w};
            const float mm[4]  = {mv.x, mv.y, mv.z, mv.w};
            #pragma unroll
            for (int k = 0; k < 4; ++k) {
                const float zn0 = wr1 * q01[k] + wr2 * q00[k];
                const float zn1 = wr1 * q11[k] + wr2 * q10[k];
                const float d0  = wc1 * hh0[k] + wc2 * hh0[k + 1] - zn0;
                const float d1  = wc1 * hh1[k] + wc2 * hh1[k + 1] - zn1;
                const float e   = d0 * symy + d1 * symx;
                const float w   = (j0 + k >= a) ? mm[k] : 0.0f;
                acc += w * e * e;
            }
        }
    }

    // Block reduction: wave64 shuffle, then LDS across the 4 waves.
    #pragma unroll
    for (int off = 32; off > 0; off >>= 1)
        acc += __shfl_down(acc, off, 64);
    __shared__ float part[4];
    const int lane = tid & 63;
    const int wv   = tid >> 6;
    if (lane == 0) part[wv] = acc;
    __syncthreads();
    if (tid == 0) {
        const float s = part[0] + part[1] + part[2] + part[3];
        partials[b * NCHUNK + blockIdx.x] = s / (cnt * (float)NB);
    }
}

__global__ __launch_bounds__(256) void mbfs_reduce(
    const float* __restrict__ partials, float* __restrict__ out)
{
    float v = 0.0f;
    for (int idx = threadIdx.x; idx < NBLOCKS; idx += 256) v += partials[idx];
    #pragma unroll
    for (int off = 32; off > 0; off >>= 1)
        v += __shfl_down(v, off, 64);
    __shared__ float part[4];
    const int lane = threadIdx.x & 63;
    const int wv   = threadIdx.x >> 6;
    if (lane == 0) part[wv] = v;
    __syncthreads();
    if (threadIdx.x == 0) out[0] = part[0] + part[1] + part[2] + part[3];
}

extern "C" void kernel_launch(void* const* d_in, const int* in_sizes, int n_in,
                              void* d_out, int out_size, void* d_ws, size_t ws_size,
                              hipStream_t stream) {
    const float* grid_p = (const float*)d_in[0];  // (16, 2, 512, 512)
    const float* gt_p   = (const float*)d_in[1];  // (16, 2)
    const float* gd_p   = (const float*)d_in[2];  // (16, 2)
    const float* mask_p = (const float*)d_in[3];  // (16, 512, 512)
    float* out_p = (float*)d_out;
    float* ws_p  = (float*)d_ws;                  // NBLOCKS floats of partials

    dim3 g(NCHUNK, NB);
    mbfs_main<<<g, 256, 0, stream>>>(grid_p, gt_p, gd_p, mask_p, ws_p);
    mbfs_reduce<<<1, 256, 0, stream>>>(ws_p, out_p);
}

// Round 4
// 93.169 us; speedup vs baseline: 1.0800x; 1.0477x over previous
//
#include <hip/hip_runtime.h>

#define HH 512
#define WW 512
#define NB 16
#define NRB 4                      // output rows per block
#define NCHUNK (HH / NRB)          // 128 blocks per batch item
#define NBLOCKS (NB * NCHUNK)      // 2048 partials

// One block = (batch b, 4 output rows). Branch on dx is uniform per block;
// rsub (tid>>7) is wave-uniform so the row loop is divergence-free.
// All global loads are aligned float4 and provably in-bounds:
// shifted windows use base = min((j0+shift)&~3, 504) and a per-lane
// conditional 4-rotate (static indices + cndmask) for clamped edge lanes;
// lanes whose rotate would exceed the window are fully masked-invalid.
__global__ __launch_bounds__(256) void mbfs_main(
    const float* __restrict__ grid,
    const float* __restrict__ gt,
    const float* __restrict__ gd,
    const float* __restrict__ mask,
    float* __restrict__ partials)
{
    const int b    = blockIdx.y;
    const int i0   = blockIdx.x * NRB;
    const int tid  = threadIdx.x;
    const int rsub = tid >> 7;         // wave-uniform: waves 0,1 -> 0; 2,3 -> 1
    const int j0   = (tid & 127) << 2; // 0..508, 16B aligned

    const float dx   = -8.0f * gt[2 * b + 0];
    const float dy   =  8.0f * gt[2 * b + 1];
    const float symx = gd[2 * b + 0];
    const float symy = gd[2 * b + 1];

    const float dy1f = floorf(dy);
    const float dx1f = floorf(dx);
    const int dy1 = (int)dy1f;
    const int dx1 = (int)dx1f;
    const int dy2 = dy1 + 1;
    const int dx2 = dx1 + 1;
    const float wc1 = (dx1f + 1.0f) - dx;
    const float wc2 = dx - dx1f;
    const float wr1 = (dy1f + 1.0f) - dy;
    const float wr2 = dy - dy1f;

    const float* g0 = grid + (size_t)b * 2 * HH * WW;
    const float* g1 = g0 + HH * WW;
    const float* mk = mask + (size_t)b * HH * WW;

    const int imax = HH - dy2;   // dy in [0,8) -> imax in [504,511]
    float acc = 0.0f;
    float cnt;

    if (dx > 0.0f) {
        // delta_p = g[i][j] - (wc1*z[j+dx1] + wc2*z[j+dx1+1]),
        // z[c] = wr1*g[i+dy1][c] + wr2*g[i+dy2][c]. dx1 in [0,8].
        const int jmax = WW - dx2;
        cnt = (float)imax * (float)jmax;
        const int  b0   = (j0 + dx1) & ~3;
        const int  base = min(b0, WW - 8);  // window base..base+7 <= 511
        const bool sh   = (b0 != base);     // rotate-by-4 lanes (edge)
        const int  off  = dx1 & 3;          // uniform intra-window offset

        #pragma unroll
        for (int p = 0; p < 2; ++p) {
            const int i = i0 + rsub + 2 * p;
            if (i < imax) {
                const float4 c0 = *(const float4*)(g0 + i * WW + j0);
                const float4 c1 = *(const float4*)(g1 + i * WW + j0);
                const float4 mv = *(const float4*)(mk + i * WW + j0);

                const float* A0 = g0 + (i + dy1) * WW + base;
                const float* B0 = g0 + (i + dy2) * WW + base;
                const float* A1 = g1 + (i + dy1) * WW + base;
                const float* B1 = g1 + (i + dy2) * WW + base;
                const float4 a0l = *(const float4*)(A0);
                const float4 a0h = *(const float4*)(A0 + 4);
                const float4 b0l = *(const float4*)(B0);
                const float4 b0h = *(const float4*)(B0 + 4);
                const float4 a1l = *(const float4*)(A1);
                const float4 a1h = *(const float4*)(A1 + 4);
                const float4 b1l = *(const float4*)(B1);
                const float4 b1h = *(const float4*)(B1 + 4);

                const float z0[8] = {
                    wr1 * a0l.x + wr2 * b0l.x, wr1 * a0l.y + wr2 * b0l.y,
                    wr1 * a0l.z + wr2 * b0l.z, wr1 * a0l.w + wr2 * b0l.w,
                    wr1 * a0h.x + wr2 * b0h.x, wr1 * a0h.y + wr2 * b0h.y,
                    wr1 * a0h.z + wr2 * b0h.z, wr1 * a0h.w + wr2 * b0h.w };
                const float z1[8] = {
                    wr1 * a1l.x + wr2 * b1l.x, wr1 * a1l.y + wr2 * b1l.y,
                    wr1 * a1l.z + wr2 * b1l.z, wr1 * a1l.w + wr2 * b1l.w,
                    wr1 * a1h.x + wr2 * b1h.x, wr1 * a1h.y + wr2 * b1h.y,
                    wr1 * a1h.z + wr2 * b1h.z, wr1 * a1h.w + wr2 * b1h.w };

                float y0[5], y1[5];
                #pragma unroll
                for (int m = 0; m < 5; ++m) {
                    const int iu = off + m;          // 0..7 (static)
                    const int is = min(iu + 4, 7);   // static
                    y0[m] = sh ? z0[is] : z0[iu];
                    y1[m] = sh ? z1[is] : z1[iu];
                }
                const float cc0[4] = {c0.x, c0.y, c0.z, c0.w};
                const float cc1[4] = {c1.x, c1.y, c1.z, c1.w};
                const float mm[4]  = {mv.x, mv.y, mv.z, mv.w};
                #pragma unroll
                for (int k = 0; k < 4; ++k) {
                    const float s0 = wc1 * y0[k] + wc2 * y0[k + 1];
                    const float s1 = wc1 * y1[k] + wc2 * y1[k + 1];
                    const float d0 = cc0[k] - s0;
                    const float d1 = cc1[k] - s1;
                    const float e  = d0 * symy + d1 * symx;
                    const float w  = (j0 + k < jmax) ? mm[k] : 0.0f;
                    acc += w * e * e;
                }
            }
        }
    } else {
        // delta_n = wc1*h[j] + wc2*h[clip(j+1)] - (wr1*g[i+1][j+a] + wr2*g[i][j+a])
        // with h = g[i+dy2][.], a = -dx1 in [0,8]; mask at [i+dy2][j+a];
        // valid px: j < jmax = W - a.
        const int a    = -dx1;
        const int jmax = WW - a;
        cnt = (float)imax * (float)jmax;
        const int  zb0   = (j0 + a) & ~3;
        const int  zbase = min(zb0, WW - 8);
        const bool sh    = (zb0 != zbase);
        const int  off   = a & 3;

        #pragma unroll
        for (int p = 0; p < 2; ++p) {
            const int i = i0 + rsub + 2 * p;
            if (i < imax) {
                const float* H0 = g0 + (i + dy2) * WW;
                const float* H1 = g1 + (i + dy2) * WW;
                const float4 h04 = *(const float4*)(H0 + j0);
                const float4 h14 = *(const float4*)(H1 + j0);
                const int je = min(j0 + 4, WW - 1);
                const float hh0[5] = {h04.x, h04.y, h04.z, h04.w, H0[je]};
                const float hh1[5] = {h14.x, h14.y, h14.z, h14.w, H1[je]};

                const float* R0a = g0 + (i + 1) * WW + zbase;  // weight wr1
                const float* R0b = g0 + i * WW + zbase;        // weight wr2
                const float* R1a = g1 + (i + 1) * WW + zbase;
                const float* R1b = g1 + i * WW + zbase;
                const float* MM  = mk + (i + dy2) * WW + zbase;
                const float4 r0al = *(const float4*)(R0a);
                const float4 r0ah = *(const float4*)(R0a + 4);
                const float4 r0bl = *(const float4*)(R0b);
                const float4 r0bh = *(const float4*)(R0b + 4);
                const float4 r1al = *(const float4*)(R1a);
                const float4 r1ah = *(const float4*)(R1a + 4);
                const float4 r1bl = *(const float4*)(R1b);
                const float4 r1bh = *(const float4*)(R1b + 4);
                const float4 mml  = *(const float4*)(MM);
                const float4 mmh  = *(const float4*)(MM + 4);

                const float z0[8] = {
                    wr1 * r0al.x + wr2 * r0bl.x, wr1 * r0al.y + wr2 * r0bl.y,
                    wr1 * r0al.z + wr2 * r0bl.z, wr1 * r0al.w + wr2 * r0bl.w,
                    wr1 * r0ah.x + wr2 * r0bh.x, wr1 * r0ah.y + wr2 * r0bh.y,
                    wr1 * r0ah.z + wr2 * r0bh.z, wr1 * r0ah.w + wr2 * r0bh.w };
                const float z1[8] = {
                    wr1 * r1al.x + wr2 * r1bl.x, wr1 * r1al.y + wr2 * r1bl.y,
                    wr1 * r1al.z + wr2 * r1bl.z, wr1 * r1al.w + wr2 * r1bl.w,
                    wr1 * r1ah.x + wr2 * r1bh.x, wr1 * r1ah.y + wr2 * r1bh.y,
                    wr1 * r1ah.z + wr2 * r1bh.z, wr1 * r1ah.w + wr2 * r1bh.w };
                const float zm[8] = {mml.x, mml.y, mml.z, mml.w,
                                     mmh.x, mmh.y, mmh.z, mmh.w};

                float y0[4], y1[4], ym[4];
                #pragma unroll
                for (int m = 0; m < 4; ++m) {
                    const int iu = off + m;          // 0..6 (static)
                    const int is = min(iu + 4, 7);   // static
                    y0[m] = sh ? z0[is] : z0[iu];
                    y1[m] = sh ? z1[is] : z1[iu];
                    ym[m] = sh ? zm[is] : zm[iu];
                }
                #pragma unroll
                for (int k = 0; k < 4; ++k) {
                    const float d0 = wc1 * hh0[k] + wc2 * hh0[k + 1] - y0[k];
                    const float d1 = wc1 * hh1[k] + wc2 * hh1[k + 1] - y1[k];
                    const float e  = d0 * symy + d1 * symx;
                    const float w  = (j0 + k < jmax) ? ym[k] : 0.0f;
                    acc += w * e * e;
                }
            }
        }
    }

    // Block reduction: wave64 shuffle, then LDS across the 4 waves.
    #pragma unroll
    for (int offr = 32; offr > 0; offr >>= 1)
        acc += __shfl_down(acc, offr, 64);
    __shared__ float part[4];
    const int lane = tid & 63;
    const int wv   = tid >> 6;
    if (lane == 0) part[wv] = acc;
    __syncthreads();
    if (tid == 0) {
        const float s = part[0] + part[1] + part[2] + part[3];
        partials[b * NCHUNK + blockIdx.x] = s / (cnt * (float)NB);
    }
}

__global__ __launch_bounds__(256) void mbfs_reduce(
    const float* __restrict__ partials, float* __restrict__ out)
{
    float v = 0.0f;
    for (int idx = threadIdx.x; idx < NBLOCKS; idx += 256) v += partials[idx];
    #pragma unroll
    for (int off = 32; off > 0; off >>= 1)
        v += __shfl_down(v, off, 64);
    __shared__ float part[4];
    const int lane = threadIdx.x & 63;
    const int wv   = threadIdx.x >> 6;
    if (lane == 0) part[wv] = v;
    __syncthreads();
    if (threadIdx.x == 0) out[0] = part[0] + part[1] + part[2] + part[3];
}

extern "C" void kernel_launch(void* const* d_in, const int* in_sizes, int n_in,
                              void* d_out, int out_size, void* d_ws, size_t ws_size,
                              hipStream_t stream) {
    const float* grid_p = (const float*)d_in[0];  // (16, 2, 512, 512)
    const float* gt_p   = (const float*)d_in[1];  // (16, 2)
    const float* gd_p   = (const float*)d_in[2];  // (16, 2)
    const float* mask_p = (const float*)d_in[3];  // (16, 512, 512)
    float* out_p = (float*)d_out;
    float* ws_p  = (float*)d_ws;                  // NBLOCKS floats of partials

    dim3 g(NCHUNK, NB);
    mbfs_main<<<g, 256, 0, stream>>>(grid_p, gt_p, gd_p, mask_p, ws_p);
    mbfs_reduce<<<1, 256, 0, stream>>>(ws_p, out_p);
}